// Round 12
// baseline (466.899 us; speedup 1.0000x reference)
//
#include <hip/hip_runtime.h>
#include <hip/hip_cooperative_groups.h>
#include <math.h>

namespace cg = cooperative_groups;

#define NIN 64
#define CAP 16
#define GSEG 250
#define POOL_SPLIT 8
#define BND 256            // nodes per bucket
#define CHUNK 2048         // edges per hist/scatter chunk
#define NBMAX 512          // max buckets / max chunks supported by scans

__device__ __forceinline__ float wave_reduce_sum(float v) {
    #pragma unroll
    for (int off = 32; off > 0; off >>= 1) v += __shfl_xor(v, off);
    return v;
}

__device__ __forceinline__ unsigned short f2bf(float f) {
    unsigned int u = __float_as_uint(f);
    u += 0x7FFFu + ((u >> 16) & 1u);   // round-to-nearest-even
    return (unsigned short)(u >> 16);
}
__device__ __forceinline__ float bf2f(unsigned short h) {
    return __uint_as_float(((unsigned int)h) << 16);
}
__device__ __forceinline__ float bflo(unsigned int u) { return __uint_as_float(u << 16); }
__device__ __forceinline__ float bfhi(unsigned int u) { return __uint_as_float(u & 0xFFFF0000u); }
__device__ __forceinline__ unsigned int pack2bf(float lo, float hi) {
    return (unsigned int)f2bf(lo) | ((unsigned int)f2bf(hi) << 16);
}

// 15-bit float for w in (0,1]: 5-bit exp, 10-bit mantissa.
__device__ __forceinline__ unsigned int f15enc(float w) {
    unsigned int u = __float_as_uint(w);           // w >= 0
    u += 0x0FFFu + ((u >> 13) & 1u);               // RNE to 10-bit mantissa
    int e5 = (int)(u >> 23) - 96;
    if (e5 <= 0) return 0u;                        // underflow -> 0 (negligible)
    unsigned int m = (u >> 13) & 0x3FFu;
    if (e5 > 31) { e5 = 31; m = 0x3FFu; }
    return ((unsigned int)e5 << 10) | m;
}
__device__ __forceinline__ float f15dec(unsigned int f) {
    if (f == 0u) return 0.0f;
    return __uint_as_float((((f >> 10) + 96u) << 23) | ((f & 0x3FFu) << 13));
}

// exclusive prefix of x across the 64-lane wave
__device__ __forceinline__ int wave_excl_scan_int(int x, int lane) {
    int inc = x;
    #pragma unroll
    for (int off = 1; off < 64; off <<= 1) {
        int y = __shfl_up(inc, off);
        if (lane >= off) inc += y;
    }
    return inc - x;
}

// wave0 helper: exclusive scan of src[0..nb) (global) into dst (LDS).
__device__ __forceinline__ void scan_btot(const int* __restrict__ src,
                                          int* dst, int nb, int tid) {
    if (tid < 64) {
        int v[8];
        #pragma unroll
        for (int j = 0; j < 8; ++j) {
            int idx = tid * 8 + j;
            v[j] = (idx < nb) ? src[idx] : 0;
        }
        int loc = 0;
        #pragma unroll
        for (int j = 0; j < 8; ++j) loc += v[j];
        int ex = wave_excl_scan_int(loc, tid);
        int run = ex;
        #pragma unroll
        for (int j = 0; j < 8; ++j) {
            int idx = tid * 8 + j;
            if (idx < nb) { dst[idx] = run; run += v[j]; }
        }
    }
}

struct SmScat {
    int h[NBMAX], loff[NBMAX], gdst[NBMAX], bb[NBMAX];
    uint2 recs[CHUNK];
    unsigned short rb[CHUNK];
};
struct SmBuild {
    unsigned int tile[BND * CAP];
    int scnt[BND];
    int bb[NBMAX];
    int ovl[BND];
    int nov;
};
union SMem {
    int h[NBMAX];
    SmScat scat;
    SmBuild build;
};

// One cooperative kernel: prep -> hist+deg -> scan+dinv+bounds -> scatter(bake w)
// -> build -> ovf -> gather. grid.sync() between phases replaces 5 launches.
__global__ void __launch_bounds__(256)
k_fused(const float4* __restrict__ x4, ushort* __restrict__ x16,
        float* __restrict__ out, int* __restrict__ gstart, int* __restrict__ gend,
        int* __restrict__ ovf_cnt, const int* __restrict__ row,
        const int* __restrict__ col, const float* __restrict__ ew,
        int* __restrict__ ghist, int* __restrict__ btot,
        const int* __restrict__ seg, uint2* __restrict__ bins,
        unsigned int* __restrict__ ell, float* __restrict__ deg,
        int* __restrict__ cnt, int2* __restrict__ ovf, float* __restrict__ aggf,
        ushort* __restrict__ agg16, const float* __restrict__ Wp,
        const float* __restrict__ bp, float* __restrict__ score,
        int n, int e, int nb, int nblk) {
    cg::grid_group grid = cg::this_grid();
    __shared__ SMem sm;
    int tid = threadIdx.x;
    int gsz = gridDim.x * 256;
    int gi = blockIdx.x * 256 + tid;

    // ---- P1a: x16 = bf16(x); zero deg/out/bounds/ovf_cnt ----
    {
        int tot = n * (NIN / 4);
        for (int i = gi; i < tot; i += gsz) {
            float4 v = x4[i];
            ushort4 h4;
            h4.x = f2bf(v.x); h4.y = f2bf(v.y); h4.z = f2bf(v.z); h4.w = f2bf(v.w);
            ((ushort4*)x16)[i] = h4;
        }
        for (int i = gi; i < n; i += gsz) deg[i] = 0.0f;
        for (int i = gi; i < GSEG * NIN; i += gsz) out[i] = 0.0f;
        for (int i = gi; i < GSEG; i += gsz) { gstart[i] = 0; gend[i] = 0; }
        if (gi == 0) *ovf_cnt = 0;
    }
    grid.sync();

    // ---- P1b: per-chunk LDS histogram + deg accumulation ----
    for (int blk = blockIdx.x; blk < nblk; blk += gridDim.x) {
        __syncthreads();
        for (int j = tid; j < NBMAX; j += 256) sm.h[j] = 0;
        __syncthreads();
        int base = blk * CHUNK;
        int end = base + CHUNK; if (end > e) end = e;
        for (int i = base + tid; i < end; i += 256) {
            int c = col[i];
            atomicAdd(&sm.h[c >> 8], 1);
            atomicAdd(&deg[c], ew[i]);
        }
        __syncthreads();
        for (int b = tid; b < nb; b += 256) ghist[blk * nb + b] = sm.h[b];
    }
    grid.sync();

    // ---- P2: per-bucket scan across chunks; deg -> dinv; segment bounds ----
    {
        int wid = blockIdx.x * 4 + (tid >> 6);
        int lane = tid & 63;
        int nw = gridDim.x * 4;
        for (int b = wid; b < nb; b += nw) {
            int v[8];
            #pragma unroll
            for (int j = 0; j < 8; ++j) {
                int idx = lane * 8 + j;
                v[j] = (idx < nblk) ? ghist[idx * nb + b] : 0;
            }
            int loc = 0;
            #pragma unroll
            for (int j = 0; j < 8; ++j) loc += v[j];
            int ex = wave_excl_scan_int(loc, lane);
            int run = ex;
            #pragma unroll
            for (int j = 0; j < 8; ++j) {
                int idx = lane * 8 + j;
                if (idx < nblk) { int t = v[j]; ghist[idx * nb + b] = run; run += t; }
            }
            if (lane == 63) btot[b] = ex + loc;
        }
        for (int i = gi; i < n; i += gsz) {
            deg[i] = rsqrtf(deg[i] + 1.0f);   // dinv (self-loop +1)
            int s = seg[i];
            if (i == 0 || seg[i - 1] != s) gstart[s] = i;
            if (i == n - 1 || seg[i + 1] != s) gend[s] = i + 1;
        }
    }
    grid.sync();

    // ---- P3: scatter with FULL weight baked: w = ew * dinv[r] * dinv[c] ----
    for (int blk = blockIdx.x; blk < nblk; blk += gridDim.x) {
        __syncthreads();
        for (int i = tid; i < NBMAX; i += 256) sm.scat.h[i] = 0;
        __syncthreads();
        int base = blk * CHUNK;
        int end = base + CHUNK; if (end > e) end = e;
        int cntc = end - base;
        for (int i = base + tid; i < end; i += 256) atomicAdd(&sm.scat.h[col[i] >> 8], 1);
        __syncthreads();
        if (tid < 64) {
            int v[8];
            #pragma unroll
            for (int j = 0; j < 8; ++j) {
                int idx = tid * 8 + j;
                v[j] = (idx < nb) ? sm.scat.h[idx] : 0;
            }
            int loc = 0;
            #pragma unroll
            for (int j = 0; j < 8; ++j) loc += v[j];
            int ex = wave_excl_scan_int(loc, tid);
            int run = ex;
            #pragma unroll
            for (int j = 0; j < 8; ++j) {
                int idx = tid * 8 + j;
                if (idx < nb) { sm.scat.loff[idx] = run; run += v[j]; }
            }
        }
        scan_btot(btot, sm.scat.bb, nb, tid);
        __syncthreads();
        for (int b = tid; b < nb; b += 256)
            sm.scat.gdst[b] = sm.scat.bb[b] + ghist[blk * nb + b];
        for (int i = tid; i < NBMAX; i += 256) sm.scat.h[i] = 0;
        __syncthreads();
        for (int i = base + tid; i < end; i += 256) {
            int c = col[i], r = row[i];
            int b = c >> 8;
            float w = ew[i] * deg[r] * deg[c];   // deg holds dinv
            uint2 rec;
            rec.x = (unsigned int)r;
            rec.y = ((unsigned int)(c & (BND - 1)) << 15) | f15enc(w);
            int k = atomicAdd(&sm.scat.h[b], 1);
            int idx = sm.scat.loff[b] + k;
            sm.scat.recs[idx] = rec;
            sm.scat.rb[idx] = (unsigned short)b;
        }
        __syncthreads();
        for (int i = tid; i < cntc; i += 256) {
            int b = sm.scat.rb[i];
            bins[(size_t)sm.scat.gdst[b] + (i - sm.scat.loff[b])] = sm.scat.recs[i];
        }
    }
    grid.sync();

    // ---- P4: build ELL per bucket; zero aggf rows of own overflowed nodes ----
    for (int b = blockIdx.x; b < nb; b += gridDim.x) {
        __syncthreads();
        int c0 = b << 8;
        int nn = n - c0; if (nn > BND) nn = BND;
        sm.build.scnt[tid] = 0;
        if (tid == 0) sm.build.nov = 0;
        for (int i = tid; i < BND * CAP; i += 256) sm.build.tile[i] = 0u;
        scan_btot(btot, sm.build.bb, nb, tid);
        __syncthreads();
        int s0 = sm.build.bb[b], tot = btot[b];
        for (int i = tid; i < tot; i += 256) {
            uint2 rec = bins[(size_t)s0 + i];
            int cl = (int)((rec.y >> 15) & (BND - 1));
            unsigned int w15 = rec.y & 0x7FFFu;
            int slot = atomicAdd(&sm.build.scnt[cl], 1);
            unsigned int p = (rec.x << 15) | w15;
            if (slot < CAP) {
                sm.build.tile[cl * CAP + slot] = p;
            } else {
                int oi = atomicAdd(ovf_cnt, 1);
                ovf[oi] = make_int2(c0 + cl, (int)p);
            }
        }
        __syncthreads();
        for (int i = tid; i < nn * CAP; i += 256)
            ell[(size_t)c0 * CAP + i] = sm.build.tile[i];
        if (tid < nn) {
            cnt[c0 + tid] = sm.build.scnt[tid];
            if (sm.build.scnt[tid] > CAP) {
                int k = atomicAdd(&sm.build.nov, 1);
                sm.build.ovl[k] = tid;
            }
        }
        __syncthreads();
        int nov = sm.build.nov;
        for (int k = 0; k < nov; ++k) {
            if (tid < NIN) aggf[(size_t)(c0 + sm.build.ovl[k]) * NIN + tid] = 0.0f;
        }
    }
    grid.sync();

    // ---- P5: replay overflow edges (weights already full) ----
    {
        int nov = *ovf_cnt;
        int wid = blockIdx.x * 4 + (tid >> 6);
        int lane = tid & 63;
        int nw = gridDim.x * 4;
        for (int i = wid; i < nov; i += nw) {
            int2 ov = ovf[i];
            int c = ov.x;
            unsigned int p = (unsigned int)ov.y;
            int r = (int)(p >> 15);
            float w = f15dec(p & 0x7FFFu);
            atomicAdd(&aggf[(size_t)c * NIN + lane], w * bf2f(x16[(size_t)r * NIN + lane]));
        }
    }
    grid.sync();

    // ---- P6: gather. 8 nodes/wave, 8 lanes/node, uint4/lane. No deg gathers. ----
    {
        int gw = blockIdx.x * 4 + (tid >> 6);
        int gnw = gridDim.x * 4;
        int lane = tid & 63;
        int o = lane >> 3, l = lane & 7;
        int ngrp = (n + 7) / 8;
        const float4* wp4 = (const float4*)Wp;
        float4 w0 = wp4[2 * l], w1 = wp4[2 * l + 1];
        float bp0 = bp[0];
        const uint2* ell2 = (const uint2*)ell;
        const uint4* xr4 = (const uint4*)x16;
        for (int grp = gw; grp < ngrp; grp += gnw) {
            int c = grp * 8 + o;
            bool valid = c < n;
            int cc = valid ? c : (n - 1);
            int cr = cnt[cc];
            int m = valid ? (cr < CAP ? cr : CAP) : 0;
            float di = deg[cc];                       // dinv
            uint2 pe = ell2[(size_t)cc * 8 + l];
            int pr0 = (int)(pe.x >> 15);
            float pw0 = f15dec(pe.x & 0x7FFFu);       // full weight
            int pr1 = (int)(pe.y >> 15);
            float pw1 = f15dec(pe.y & 0x7FFFu);
            uint4 xs = xr4[(size_t)cc * 8 + l];
            float s2 = di * di;
            float a0 = s2 * bflo(xs.x), a1 = s2 * bfhi(xs.x);
            float a2 = s2 * bflo(xs.y), a3 = s2 * bfhi(xs.y);
            float a4 = s2 * bflo(xs.z), a5 = s2 * bfhi(xs.z);
            float a6 = s2 * bflo(xs.w), a7 = s2 * bfhi(xs.w);
            int base = lane & 56;
            #pragma unroll
            for (int k = 0; k < 8; ++k) {
                int rk = __shfl((k & 1) ? pr1 : pr0, base + (k >> 1));
                float wk = __shfl((k & 1) ? pw1 : pw0, base + (k >> 1));
                bool v = k < m;
                int r = v ? rk : 0;
                float w = v ? wk : 0.0f;
                uint4 xr = xr4[(size_t)r * 8 + l];
                a0 = fmaf(w, bflo(xr.x), a0); a1 = fmaf(w, bfhi(xr.x), a1);
                a2 = fmaf(w, bflo(xr.y), a2); a3 = fmaf(w, bfhi(xr.y), a3);
                a4 = fmaf(w, bflo(xr.z), a4); a5 = fmaf(w, bfhi(xr.z), a5);
                a6 = fmaf(w, bflo(xr.w), a6); a7 = fmaf(w, bfhi(xr.w), a7);
            }
            if (__any(m > 8)) {
                #pragma unroll
                for (int k = 8; k < CAP; ++k) {
                    int rk = __shfl((k & 1) ? pr1 : pr0, base + (k >> 1));
                    float wk = __shfl((k & 1) ? pw1 : pw0, base + (k >> 1));
                    bool v = k < m;
                    int r = v ? rk : 0;
                    float w = v ? wk : 0.0f;
                    uint4 xr = xr4[(size_t)r * 8 + l];
                    a0 = fmaf(w, bflo(xr.x), a0); a1 = fmaf(w, bfhi(xr.x), a1);
                    a2 = fmaf(w, bflo(xr.y), a2); a3 = fmaf(w, bfhi(xr.y), a3);
                    a4 = fmaf(w, bflo(xr.z), a4); a5 = fmaf(w, bfhi(xr.z), a5);
                    a6 = fmaf(w, bflo(xr.w), a6); a7 = fmaf(w, bfhi(xr.w), a7);
                }
            }
            if (valid && cr > CAP) {
                const float4* af4 = (const float4*)aggf;
                float4 f0 = af4[(size_t)cc * 16 + 2 * l];
                float4 f1 = af4[(size_t)cc * 16 + 2 * l + 1];
                a0 += f0.x; a1 += f0.y; a2 += f0.z; a3 += f0.w;
                a4 += f1.x; a5 += f1.y; a6 += f1.z; a7 += f1.w;
            }
            if (valid) {
                uint4 ho;
                ho.x = pack2bf(a0, a1); ho.y = pack2bf(a2, a3);
                ho.z = pack2bf(a4, a5); ho.w = pack2bf(a6, a7);
                ((uint4*)agg16)[(size_t)cc * 8 + l] = ho;
            }
            float part = a0 * w0.x + a1 * w0.y + a2 * w0.z + a3 * w0.w
                       + a4 * w1.x + a5 * w1.y + a6 * w1.z + a7 * w1.w;
            part += __shfl_xor(part, 1);
            part += __shfl_xor(part, 2);
            part += __shfl_xor(part, 4);
            if (l == 0 && valid) score[c] = part + bp0;
        }
    }
}

// POOL_SPLIT blocks per graph. Fused per-graph softmax; W column in 16 NAMED
// float4s; node agg row staged via LDS broadcast; 4 FMA chains; prefetch.
#define WLOAD(i) float4 wq##i = make_float4(We[(4*(i)+0)*NIN+lane], We[(4*(i)+1)*NIN+lane], \
                                            We[(4*(i)+2)*NIN+lane], We[(4*(i)+3)*NIN+lane]);
#define WSTEP(i) { float4 av = *(const float4*)&als[wv][4*(i)]; \
    e0 = fmaf(av.x, wq##i.x, e0); e1 = fmaf(av.y, wq##i.y, e1); \
    e2 = fmaf(av.z, wq##i.z, e2); e3 = fmaf(av.w, wq##i.w, e3); }

__global__ void __launch_bounds__(256)
k_pool(const ushort* __restrict__ agg16, const float* __restrict__ score,
       const float* __restrict__ We, const float* __restrict__ be,
       const int* __restrict__ gstart, const int* __restrict__ gend,
       float* __restrict__ out) {
    int g = blockIdx.x / POOL_SPLIT;
    int p = blockIdx.x % POOL_SPLIT;
    int tid = threadIdx.x;
    int wv = tid >> 6, lane = tid & 63;
    int s = gstart[g], e = gend[g];

    __shared__ float red[4];
    __shared__ float bc;

    float mx = -3.402823466e38f;
    for (int i = s + tid; i < e; i += 256) mx = fmaxf(mx, score[i]);
    #pragma unroll
    for (int off = 32; off > 0; off >>= 1) mx = fmaxf(mx, __shfl_xor(mx, off));
    if (lane == 0) red[wv] = mx;
    __syncthreads();
    if (tid == 0) bc = fmaxf(fmaxf(red[0], red[1]), fmaxf(red[2], red[3]));
    __syncthreads();
    float m = bc;
    __syncthreads();

    float sm = 0.0f;
    for (int i = s + tid; i < e; i += 256) sm += __expf(score[i] - m);
    sm = wave_reduce_sum(sm);
    if (lane == 0) red[wv] = sm;
    __syncthreads();
    if (tid == 0) bc = red[0] + red[1] + red[2] + red[3];
    __syncthreads();
    float invz = (bc > 0.0f) ? 1.0f / bc : 0.0f;

    WLOAD(0) WLOAD(1) WLOAD(2) WLOAD(3) WLOAD(4) WLOAD(5) WLOAD(6) WLOAD(7)
    WLOAD(8) WLOAD(9) WLOAD(10) WLOAD(11) WLOAD(12) WLOAD(13) WLOAD(14) WLOAD(15)
    float bj = be[lane];

    __shared__ float als[4][NIN];
    __shared__ float part[4][NIN];

    const int stride = POOL_SPLIT * 4;
    int n = s + p * 4 + wv;
    float acc = 0.0f;

    float a_cur = 0.0f, sw_cur = 0.0f;
    if (n < e) {
        a_cur = bf2f(agg16[(size_t)n * NIN + lane]);
        sw_cur = __expf(score[n] - m) * invz;
    }
    while (n < e) {
        int nn = n + stride;
        bool vn = nn < e;
        int ni = vn ? nn : n;
        float a_nxt = bf2f(agg16[(size_t)ni * NIN + lane]);   // prefetch
        float sw_nxt = __expf(score[ni] - m) * invz;

        als[wv][lane] = a_cur;
        float e0 = bj, e1 = 0.0f, e2 = 0.0f, e3 = 0.0f;
        WSTEP(0) WSTEP(1) WSTEP(2) WSTEP(3) WSTEP(4) WSTEP(5) WSTEP(6) WSTEP(7)
        WSTEP(8) WSTEP(9) WSTEP(10) WSTEP(11) WSTEP(12) WSTEP(13) WSTEP(14) WSTEP(15)
        float emb = fmaxf(e0 + e1 + e2 + e3, 0.0f);
        acc = fmaf(sw_cur, emb, acc);

        a_cur = a_nxt; sw_cur = sw_nxt;
        n = nn;
    }
    part[wv][lane] = acc;
    __syncthreads();
    if (wv == 0) {
        float r = part[0][lane] + part[1][lane] + part[2][lane] + part[3][lane];
        atomicAdd(&out[(size_t)g * NIN + lane], r);
    }
}

extern "C" void kernel_launch(void* const* d_in, const int* in_sizes, int n_in,
                              void* d_out, int out_size, void* d_ws, size_t ws_size,
                              hipStream_t stream) {
    const float* x  = (const float*)d_in[0];
    const float* We = (const float*)d_in[1];
    const float* be = (const float*)d_in[2];
    const float* Wp = (const float*)d_in[3];
    const float* bp = (const float*)d_in[4];
    const float* ew = (const float*)d_in[5];
    const int* eidx = (const int*)d_in[6];
    const int* seg  = (const int*)d_in[7];

    int N = in_sizes[0] / NIN;
    int E = in_sizes[5];
    const int* row = eidx;
    const int* col = eidx + E;
    int nb   = (N + BND - 1) / BND;       // 391
    int nblk = (E + CHUNK - 1) / CHUNK;   // 391

    char* w = (char*)d_ws;
    auto alloc = [&](size_t bytes) {
        char* p = w;
        w += (bytes + 255) & ~(size_t)255;
        return p;
    };
    float*          aggf    = (float*)alloc((size_t)N * NIN * sizeof(float));
    unsigned short* x16     = (unsigned short*)alloc((size_t)N * NIN * sizeof(short));
    unsigned short* agg16   = (unsigned short*)alloc((size_t)N * NIN * sizeof(short));
    float*          deg     = (float*)alloc((size_t)N * sizeof(float));
    int*            cnt     = (int*)  alloc((size_t)N * sizeof(int));
    unsigned int*   ell     = (unsigned int*)alloc((size_t)N * CAP * sizeof(unsigned int));
    uint2*          bins    = (uint2*)alloc((size_t)E * sizeof(uint2));
    int*            ghist   = (int*)  alloc((size_t)nblk * nb * sizeof(int));
    int*            btot    = (int*)  alloc((size_t)nb * sizeof(int));
    int2*           ovf     = (int2*) alloc((size_t)(E / 4) * sizeof(int2));
    int*            ovf_cnt = (int*)  alloc(256);
    float*          score   = (float*)alloc((size_t)N * sizeof(float));
    int*            gstart  = (int*)  alloc(GSEG * sizeof(int));
    int*            gend    = (int*)  alloc(GSEG * sizeof(int));
    float* out = (float*)d_out;

    // cooperative grid sizing: co-resident max (deterministic queries only)
    int dev = 0;
    hipGetDevice(&dev);
    hipDeviceProp_t prop;
    hipGetDeviceProperties(&prop, dev);
    int maxb = 0;
    hipOccupancyMaxActiveBlocksPerMultiprocessor(&maxb, (const void*)k_fused, 256, 0);
    if (maxb < 1) maxb = 1;
    long long grid_ll = (long long)maxb * (long long)prop.multiProcessorCount;
    if (grid_ll > 2048) grid_ll = 2048;
    unsigned int grid = (unsigned int)grid_ll;

    const float4* x4 = (const float4*)x;
    ushort* x16u = (ushort*)x16;
    ushort* agg16u = (ushort*)agg16;
    void* args[] = {
        (void*)&x4, (void*)&x16u, (void*)&out, (void*)&gstart, (void*)&gend,
        (void*)&ovf_cnt, (void*)&row, (void*)&col, (void*)&ew,
        (void*)&ghist, (void*)&btot, (void*)&seg, (void*)&bins,
        (void*)&ell, (void*)&deg, (void*)&cnt, (void*)&ovf, (void*)&aggf,
        (void*)&agg16u, (void*)&Wp, (void*)&bp, (void*)&score,
        (void*)&N, (void*)&E, (void*)&nb, (void*)&nblk
    };
    hipLaunchCooperativeKernel((const void*)k_fused, dim3(grid), dim3(256),
                               args, 0, stream);
    k_pool<<<GSEG * POOL_SPLIT, 256, 0, stream>>>(agg16, score, We, be,
                                                  gstart, gend, out);
}

// Round 13
// 129.264 us; speedup vs baseline: 3.6120x; 3.6120x over previous
//
#include <hip/hip_runtime.h>
#include <math.h>

#define NIN 64
#define CAP 16
#define GSEG 250
#define POOL_SPLIT 8
#define BND 128            // nodes per bucket
#define BSH 7              // log2(BND)
#define CHUNK 2048         // edges per hist/scatter chunk
#define NBMAX 1024         // max buckets
#define OVRMAX 256         // per-bucket overflow side-list
#define TS 17              // padded LDS tile stride (uints per node)

__device__ __forceinline__ float wave_reduce_sum(float v) {
    #pragma unroll
    for (int off = 32; off > 0; off >>= 1) v += __shfl_xor(v, off);
    return v;
}

__device__ __forceinline__ unsigned short f2bf(float f) {
    unsigned int u = __float_as_uint(f);
    u += 0x7FFFu + ((u >> 16) & 1u);   // round-to-nearest-even
    return (unsigned short)(u >> 16);
}
__device__ __forceinline__ float bf2f(unsigned short h) {
    return __uint_as_float(((unsigned int)h) << 16);
}
__device__ __forceinline__ float bflo(unsigned int u) { return __uint_as_float(u << 16); }
__device__ __forceinline__ float bfhi(unsigned int u) { return __uint_as_float(u & 0xFFFF0000u); }
__device__ __forceinline__ unsigned int pack2bf(float lo, float hi) {
    return (unsigned int)f2bf(lo) | ((unsigned int)f2bf(hi) << 16);
}

// 15-bit float for w in (0,1]: 5-bit exp, 10-bit mantissa.
__device__ __forceinline__ unsigned int f15enc(float w) {
    unsigned int u = __float_as_uint(w);           // w >= 0
    u += 0x0FFFu + ((u >> 13) & 1u);               // RNE to 10-bit mantissa
    int e5 = (int)(u >> 23) - 96;
    if (e5 <= 0) return 0u;                        // underflow -> 0 (negligible)
    unsigned int m = (u >> 13) & 0x3FFu;
    if (e5 > 31) { e5 = 31; m = 0x3FFu; }
    return ((unsigned int)e5 << 10) | m;
}
__device__ __forceinline__ float f15dec(unsigned int f) {
    if (f == 0u) return 0.0f;
    return __uint_as_float((((f >> 10) + 96u) << 23) | ((f & 0x3FFu) << 13));
}

// exclusive prefix of x across the 64-lane wave
__device__ __forceinline__ int wave_excl_scan_int(int x, int lane) {
    int inc = x;
    #pragma unroll
    for (int off = 1; off < 64; off <<= 1) {
        int y = __shfl_up(inc, off);
        if (lane >= off) inc += y;
    }
    return inc - x;
}

// wave0: exclusive scan of src[0..nb) (nb <= 1024) into dst (LDS).
__device__ __forceinline__ void scan_btot(const int* __restrict__ src,
                                          int* dst, int nb, int tid) {
    if (tid < 64) {
        int v[16];
        #pragma unroll
        for (int j = 0; j < 16; ++j) {
            int idx = tid * 16 + j;
            v[j] = (idx < nb) ? src[idx] : 0;
        }
        int loc = 0;
        #pragma unroll
        for (int j = 0; j < 16; ++j) loc += v[j];
        int ex = wave_excl_scan_int(loc, tid);
        int run = ex;
        #pragma unroll
        for (int j = 0; j < 16; ++j) {
            int idx = tid * 16 + j;
            if (idx < nb) { dst[idx] = run; run += v[j]; }
        }
    }
}

// prep: x16 = bf16(x); zero deg/out/bounds; per-chunk LDS histogram.
__global__ void __launch_bounds__(256)
k_prep(ushort4* __restrict__ x164, const float4* __restrict__ x4,
       float* __restrict__ out, int* __restrict__ gstart, int* __restrict__ gend,
       float* __restrict__ deg, const int* __restrict__ col,
       int* __restrict__ ghist, int n, int e, int nb, int nblk) {
    __shared__ int h[NBMAX];
    int tid = threadIdx.x, blk = blockIdx.x;
    int i = blk * 256 + tid;
    int tot = n * (NIN / 4);
    if (i < tot) {
        float4 v = x4[i];
        ushort4 hh;
        hh.x = f2bf(v.x); hh.y = f2bf(v.y); hh.z = f2bf(v.z); hh.w = f2bf(v.w);
        x164[i] = hh;
    }
    if (i < n) deg[i] = 0.0f;
    if (i < GSEG * NIN) out[i] = 0.0f;
    if (i < GSEG) { gstart[i] = 0; gend[i] = 0; }
    if (blk < nblk) {
        for (int j = tid; j < NBMAX; j += 256) h[j] = 0;
        __syncthreads();
        int base = blk * CHUNK;
        int end = base + CHUNK; if (end > e) end = e;
        for (int j = base + tid; j < end; j += 256) atomicAdd(&h[col[j] >> BSH], 1);
        __syncthreads();
        for (int b = tid; b < nb; b += 256) ghist[blk * nb + b] = h[b];
    }
}

// scanA: per-bucket exclusive scan across chunks (wave0); deg atomics over an
// edge slice; segment bounds over a node slice. All inputs from k_prep only.
__global__ void __launch_bounds__(256)
k_scanA(int* __restrict__ ghist, int* __restrict__ btot,
        const int* __restrict__ seg, int* __restrict__ gstart,
        int* __restrict__ gend, const int* __restrict__ col,
        const float* __restrict__ ew, float* __restrict__ deg,
        int nblk, int nb, int n, int e) {
    int tid = threadIdx.x;
    int b = blockIdx.x;   // grid = nb
    if (tid < 64) {
        int lane = tid;
        int v[8];
        #pragma unroll
        for (int j = 0; j < 8; ++j) {
            int idx = lane * 8 + j;
            v[j] = (idx < nblk) ? ghist[idx * nb + b] : 0;
        }
        int loc = 0;
        #pragma unroll
        for (int j = 0; j < 8; ++j) loc += v[j];
        int ex = wave_excl_scan_int(loc, lane);
        int run = ex;
        #pragma unroll
        for (int j = 0; j < 8; ++j) {
            int idx = lane * 8 + j;
            if (idx < nblk) { int t = v[j]; ghist[idx * nb + b] = run; run += t; }
        }
        if (lane == 63) btot[b] = ex + loc;
    }
    int gsz = gridDim.x * 256;
    for (int i = b * 256 + tid; i < e; i += gsz) atomicAdd(&deg[col[i]], ew[i]);
    for (int i = b * 256 + tid; i < n; i += gsz) {
        int s = seg[i];
        if (i == 0 || seg[i - 1] != s) gstart[s] = i;
        if (i == n - 1 || seg[i + 1] != s) gend[s] = i + 1;
    }
}

// scatter: bake FULL weight w = ew * dinv[r] * dinv[c]; chunk sorted by bucket
// in LDS; copied out as per-bucket contiguous runs.
__global__ void __launch_bounds__(256)
k_scatter(const int* __restrict__ row, const int* __restrict__ col,
          const float* __restrict__ ew, const float* __restrict__ deg,
          const int* __restrict__ ghist, const int* __restrict__ btot,
          uint2* __restrict__ bins, int e, int nb) {
    __shared__ int h[NBMAX];
    __shared__ int loff[NBMAX];
    __shared__ int gdst[NBMAX];
    __shared__ int bb[NBMAX];
    __shared__ uint2 recs[CHUNK];
    __shared__ unsigned short rb[CHUNK];
    int tid = threadIdx.x, blk = blockIdx.x;
    int base = blk * CHUNK;
    int end = base + CHUNK; if (end > e) end = e;
    int cntc = end - base;

    for (int i = tid; i < NBMAX; i += 256) h[i] = 0;
    __syncthreads();
    for (int i = base + tid; i < end; i += 256) atomicAdd(&h[col[i] >> BSH], 1);
    __syncthreads();
    if (tid < 64) {
        int v[16];
        #pragma unroll
        for (int j = 0; j < 16; ++j) {
            int idx = tid * 16 + j;
            v[j] = (idx < nb) ? h[idx] : 0;
        }
        int loc = 0;
        #pragma unroll
        for (int j = 0; j < 16; ++j) loc += v[j];
        int ex = wave_excl_scan_int(loc, tid);
        int run = ex;
        #pragma unroll
        for (int j = 0; j < 16; ++j) {
            int idx = tid * 16 + j;
            if (idx < nb) { loff[idx] = run; run += v[j]; }
        }
    }
    scan_btot(btot, bb, nb, tid);
    __syncthreads();
    for (int b = tid; b < nb; b += 256) gdst[b] = bb[b] + ghist[blk * nb + b];
    for (int i = tid; i < NBMAX; i += 256) h[i] = 0;
    __syncthreads();
    for (int i = base + tid; i < end; i += 256) {
        int c = col[i], r = row[i];
        int b = c >> BSH;
        float w = ew[i] * rsqrtf(deg[r] + 1.0f) * rsqrtf(deg[c] + 1.0f);
        uint2 rec;
        rec.x = (unsigned int)r;
        rec.y = ((unsigned int)(c & (BND - 1)) << 15) | f15enc(w);
        int k = atomicAdd(&h[b], 1);
        int idx = loff[b] + k;
        recs[idx] = rec;
        rb[idx] = (unsigned short)b;
    }
    __syncthreads();
    for (int i = tid; i < cntc; i += 256) {
        int b = rb[i];
        bins[(size_t)gdst[b] + (i - loff[b])] = recs[i];
    }
}

// Fused build+gather: one block per 128-node bucket. Build ELL in LDS
// (stride-17 padded; overflow -> LDS side list), then gather straight from
// LDS: 8 nodes/wave, 8 lanes/node, uint4 (8 bf16) x-rows. No global ELL.
__global__ void __launch_bounds__(256)
k_bg(const uint2* __restrict__ bins, const int* __restrict__ btot,
     const float* __restrict__ deg, const ushort* __restrict__ x16,
     ushort* __restrict__ agg16, const float* __restrict__ Wp,
     const float* __restrict__ bp, float* __restrict__ score, int n, int nb) {
    __shared__ unsigned int tile[BND * TS];
    __shared__ int scnt[BND];
    __shared__ int bb[NBMAX];
    __shared__ int ovr_cl[OVRMAX];
    __shared__ unsigned int ovr_rec[OVRMAX];
    __shared__ int ovn;
    int tid = threadIdx.x;
    int b = blockIdx.x;
    int c0 = b << BSH;

    if (tid < BND) scnt[tid] = 0;
    if (tid == 0) ovn = 0;
    scan_btot(btot, bb, nb, tid);
    __syncthreads();

    int s0 = bb[b], tot = btot[b];
    for (int i = tid; i < tot; i += 256) {
        uint2 rec = bins[(size_t)s0 + i];
        int cl = (int)((rec.y >> 15) & (BND - 1));
        unsigned int p = (rec.x << 15) | (rec.y & 0x7FFFu);
        int slot = atomicAdd(&scnt[cl], 1);
        if (slot < CAP) {
            tile[cl * TS + slot] = p;
        } else {
            int oi = atomicAdd(&ovn, 1);
            if (oi < OVRMAX) { ovr_cl[oi] = cl; ovr_rec[oi] = p; }
        }
    }
    __syncthreads();

    int lane = tid & 63, wv = tid >> 6;
    int o = lane >> 3, l = lane & 7;
    const float4* wp4 = (const float4*)Wp;
    float4 w0 = wp4[2 * l], w1 = wp4[2 * l + 1];
    float bp0 = bp[0];
    const uint4* xr4 = (const uint4*)x16;
    int nov = ovn;

    #pragma unroll
    for (int it = 0; it < BND / 32; ++it) {
        int bl = it * 32 + wv * 8;          // first local node of this wave
        int nl = bl + o;
        int c = c0 + nl;
        bool valid = c < n;
        int cc = valid ? c : (n - 1);
        int cr = scnt[nl];
        int m = valid ? (cr < CAP ? cr : CAP) : 0;
        float di = rsqrtf(deg[cc] + 1.0f);

        unsigned int u0 = tile[nl * TS + 2 * l];
        unsigned int u1 = tile[nl * TS + 2 * l + 1];
        int pr0 = (int)(u0 >> 15);
        float pw0 = f15dec(u0 & 0x7FFFu);   // full weight
        int pr1 = (int)(u1 >> 15);
        float pw1 = f15dec(u1 & 0x7FFFu);

        uint4 xs = xr4[(size_t)cc * 8 + l];
        float s2 = di * di;
        float a0 = s2 * bflo(xs.x), a1 = s2 * bfhi(xs.x);
        float a2 = s2 * bflo(xs.y), a3 = s2 * bfhi(xs.y);
        float a4 = s2 * bflo(xs.z), a5 = s2 * bfhi(xs.z);
        float a6 = s2 * bflo(xs.w), a7 = s2 * bfhi(xs.w);

        int base = lane & 56;
        #pragma unroll
        for (int k = 0; k < 8; ++k) {
            int rk = __shfl((k & 1) ? pr1 : pr0, base + (k >> 1));
            float wk = __shfl((k & 1) ? pw1 : pw0, base + (k >> 1));
            bool v = k < m;
            int r = v ? rk : 0;
            float w = v ? wk : 0.0f;
            uint4 xr = xr4[(size_t)r * 8 + l];
            a0 = fmaf(w, bflo(xr.x), a0); a1 = fmaf(w, bfhi(xr.x), a1);
            a2 = fmaf(w, bflo(xr.y), a2); a3 = fmaf(w, bfhi(xr.y), a3);
            a4 = fmaf(w, bflo(xr.z), a4); a5 = fmaf(w, bfhi(xr.z), a5);
            a6 = fmaf(w, bflo(xr.w), a6); a7 = fmaf(w, bfhi(xr.w), a7);
        }
        if (__any(m > 8)) {
            #pragma unroll
            for (int k = 8; k < CAP; ++k) {
                int rk = __shfl((k & 1) ? pr1 : pr0, base + (k >> 1));
                float wk = __shfl((k & 1) ? pw1 : pw0, base + (k >> 1));
                bool v = k < m;
                int r = v ? rk : 0;
                float w = v ? wk : 0.0f;
                uint4 xr = xr4[(size_t)r * 8 + l];
                a0 = fmaf(w, bflo(xr.x), a0); a1 = fmaf(w, bfhi(xr.x), a1);
                a2 = fmaf(w, bflo(xr.y), a2); a3 = fmaf(w, bfhi(xr.y), a3);
                a4 = fmaf(w, bflo(xr.z), a4); a5 = fmaf(w, bfhi(xr.z), a5);
                a6 = fmaf(w, bflo(xr.w), a6); a7 = fmaf(w, bfhi(xr.w), a7);
            }
        }
        // overflow side-list (rare: deg > CAP)
        for (int i = 0; i < nov; ++i) {
            int cl = ovr_cl[i];
            if (cl >= bl && cl < bl + 8) {
                unsigned int rec = ovr_rec[i];
                int r = (int)(rec >> 15);
                float wvv = f15dec(rec & 0x7FFFu);
                float wm = (cl == nl) ? wvv : 0.0f;
                uint4 xr = xr4[(size_t)r * 8 + l];
                a0 = fmaf(wm, bflo(xr.x), a0); a1 = fmaf(wm, bfhi(xr.x), a1);
                a2 = fmaf(wm, bflo(xr.y), a2); a3 = fmaf(wm, bfhi(xr.y), a3);
                a4 = fmaf(wm, bflo(xr.z), a4); a5 = fmaf(wm, bfhi(xr.z), a5);
                a6 = fmaf(wm, bflo(xr.w), a6); a7 = fmaf(wm, bfhi(xr.w), a7);
            }
        }

        if (valid) {
            uint4 ho;
            ho.x = pack2bf(a0, a1); ho.y = pack2bf(a2, a3);
            ho.z = pack2bf(a4, a5); ho.w = pack2bf(a6, a7);
            ((uint4*)agg16)[(size_t)cc * 8 + l] = ho;
        }
        float part = a0 * w0.x + a1 * w0.y + a2 * w0.z + a3 * w0.w
                   + a4 * w1.x + a5 * w1.y + a6 * w1.z + a7 * w1.w;
        part += __shfl_xor(part, 1);
        part += __shfl_xor(part, 2);
        part += __shfl_xor(part, 4);
        if (l == 0 && valid) score[c] = part + bp0;
    }
}

// POOL_SPLIT blocks per graph. Fused per-graph softmax; W column in 16 NAMED
// float4s; node agg row staged via LDS broadcast; 4 FMA chains; prefetch.
#define WLOAD(i) float4 wq##i = make_float4(We[(4*(i)+0)*NIN+lane], We[(4*(i)+1)*NIN+lane], \
                                            We[(4*(i)+2)*NIN+lane], We[(4*(i)+3)*NIN+lane]);
#define WSTEP(i) { float4 av = *(const float4*)&als[wv][4*(i)]; \
    e0 = fmaf(av.x, wq##i.x, e0); e1 = fmaf(av.y, wq##i.y, e1); \
    e2 = fmaf(av.z, wq##i.z, e2); e3 = fmaf(av.w, wq##i.w, e3); }

__global__ void __launch_bounds__(256)
k_pool(const ushort* __restrict__ agg16, const float* __restrict__ score,
       const float* __restrict__ We, const float* __restrict__ be,
       const int* __restrict__ gstart, const int* __restrict__ gend,
       float* __restrict__ out) {
    int g = blockIdx.x / POOL_SPLIT;
    int p = blockIdx.x % POOL_SPLIT;
    int tid = threadIdx.x;
    int wv = tid >> 6, lane = tid & 63;
    int s = gstart[g], e = gend[g];

    __shared__ float red[4];
    __shared__ float bc;

    float mx = -3.402823466e38f;
    for (int i = s + tid; i < e; i += 256) mx = fmaxf(mx, score[i]);
    #pragma unroll
    for (int off = 32; off > 0; off >>= 1) mx = fmaxf(mx, __shfl_xor(mx, off));
    if (lane == 0) red[wv] = mx;
    __syncthreads();
    if (tid == 0) bc = fmaxf(fmaxf(red[0], red[1]), fmaxf(red[2], red[3]));
    __syncthreads();
    float m = bc;
    __syncthreads();

    float sm = 0.0f;
    for (int i = s + tid; i < e; i += 256) sm += __expf(score[i] - m);
    sm = wave_reduce_sum(sm);
    if (lane == 0) red[wv] = sm;
    __syncthreads();
    if (tid == 0) bc = red[0] + red[1] + red[2] + red[3];
    __syncthreads();
    float invz = (bc > 0.0f) ? 1.0f / bc : 0.0f;

    WLOAD(0) WLOAD(1) WLOAD(2) WLOAD(3) WLOAD(4) WLOAD(5) WLOAD(6) WLOAD(7)
    WLOAD(8) WLOAD(9) WLOAD(10) WLOAD(11) WLOAD(12) WLOAD(13) WLOAD(14) WLOAD(15)
    float bj = be[lane];

    __shared__ float als[4][NIN];
    __shared__ float part[4][NIN];

    const int stride = POOL_SPLIT * 4;
    int n = s + p * 4 + wv;
    float acc = 0.0f;

    float a_cur = 0.0f, sw_cur = 0.0f;
    if (n < e) {
        a_cur = bf2f(agg16[(size_t)n * NIN + lane]);
        sw_cur = __expf(score[n] - m) * invz;
    }
    while (n < e) {
        int nn = n + stride;
        bool vn = nn < e;
        int ni = vn ? nn : n;
        float a_nxt = bf2f(agg16[(size_t)ni * NIN + lane]);   // prefetch
        float sw_nxt = __expf(score[ni] - m) * invz;

        als[wv][lane] = a_cur;
        float e0 = bj, e1 = 0.0f, e2 = 0.0f, e3 = 0.0f;
        WSTEP(0) WSTEP(1) WSTEP(2) WSTEP(3) WSTEP(4) WSTEP(5) WSTEP(6) WSTEP(7)
        WSTEP(8) WSTEP(9) WSTEP(10) WSTEP(11) WSTEP(12) WSTEP(13) WSTEP(14) WSTEP(15)
        float emb = fmaxf(e0 + e1 + e2 + e3, 0.0f);
        acc = fmaf(sw_cur, emb, acc);

        a_cur = a_nxt; sw_cur = sw_nxt;
        n = nn;
    }
    part[wv][lane] = acc;
    __syncthreads();
    if (wv == 0) {
        float r = part[0][lane] + part[1][lane] + part[2][lane] + part[3][lane];
        atomicAdd(&out[(size_t)g * NIN + lane], r);
    }
}

extern "C" void kernel_launch(void* const* d_in, const int* in_sizes, int n_in,
                              void* d_out, int out_size, void* d_ws, size_t ws_size,
                              hipStream_t stream) {
    const float* x  = (const float*)d_in[0];
    const float* We = (const float*)d_in[1];
    const float* be = (const float*)d_in[2];
    const float* Wp = (const float*)d_in[3];
    const float* bp = (const float*)d_in[4];
    const float* ew = (const float*)d_in[5];
    const int* eidx = (const int*)d_in[6];
    const int* seg  = (const int*)d_in[7];

    int N = in_sizes[0] / NIN;
    int E = in_sizes[5];
    const int* row = eidx;
    const int* col = eidx + E;
    int nb   = (N + BND - 1) / BND;       // 782
    int nblk = (E + CHUNK - 1) / CHUNK;   // 391

    char* w = (char*)d_ws;
    auto alloc = [&](size_t bytes) {
        char* p = w;
        w += (bytes + 255) & ~(size_t)255;
        return p;
    };
    unsigned short* x16    = (unsigned short*)alloc((size_t)N * NIN * sizeof(short));
    unsigned short* agg16  = (unsigned short*)alloc((size_t)N * NIN * sizeof(short));
    float*          deg    = (float*)alloc((size_t)N * sizeof(float));
    uint2*          bins   = (uint2*)alloc((size_t)E * sizeof(uint2));
    int*            ghist  = (int*)  alloc((size_t)nblk * nb * sizeof(int));
    int*            btot   = (int*)  alloc((size_t)nb * sizeof(int));
    float*          score  = (float*)alloc((size_t)N * sizeof(float));
    int*            gstart = (int*)  alloc(GSEG * sizeof(int));
    int*            gend   = (int*)  alloc(GSEG * sizeof(int));
    float* out = (float*)d_out;

    int b = 256;
    int g_prep = (N * (NIN / 4) + b - 1) / b;   // 6250 >= nblk

    k_prep<<<g_prep, b, 0, stream>>>((ushort4*)x16, (const float4*)x, out, gstart,
                                     gend, deg, col, ghist, N, E, nb, nblk);
    k_scanA<<<nb, b, 0, stream>>>(ghist, btot, seg, gstart, gend, col, ew, deg,
                                  nblk, nb, N, E);
    k_scatter<<<nblk, b, 0, stream>>>(row, col, ew, deg, ghist, btot, bins, E, nb);
    k_bg<<<nb, b, 0, stream>>>(bins, btot, deg, x16, agg16, Wp, bp, score, N, nb);
    k_pool<<<GSEG * POOL_SPLIT, b, 0, stream>>>(agg16, score, We, be, gstart, gend, out);
}

// Round 14
// 93.681 us; speedup vs baseline: 4.9840x; 1.3798x over previous
//
#include <hip/hip_runtime.h>
#include <math.h>

#define NIN 64
#define CAP 16
#define GSEG 250
#define POOL_SPLIT 8
#define BND 128            // nodes per bucket
#define BSH 7              // log2(BND)
#define CHUNK 2048         // edges per hist/scatter chunk
#define NBMAX 1024         // max buckets
#define OVRMAX 256         // per-bucket overflow side-list
#define TS 17              // padded LDS tile stride (entries per node)

__device__ __forceinline__ float wave_reduce_sum(float v) {
    #pragma unroll
    for (int off = 32; off > 0; off >>= 1) v += __shfl_xor(v, off);
    return v;
}

__device__ __forceinline__ unsigned short f2bf(float f) {
    unsigned int u = __float_as_uint(f);
    u += 0x7FFFu + ((u >> 16) & 1u);   // round-to-nearest-even
    return (unsigned short)(u >> 16);
}
__device__ __forceinline__ float bf2f(unsigned short h) {
    return __uint_as_float(((unsigned int)h) << 16);
}
__device__ __forceinline__ float bflo(unsigned int u) { return __uint_as_float(u << 16); }
__device__ __forceinline__ float bfhi(unsigned int u) { return __uint_as_float(u & 0xFFFF0000u); }
__device__ __forceinline__ unsigned int pack2bf(float lo, float hi) {
    return (unsigned int)f2bf(lo) | ((unsigned int)f2bf(hi) << 16);
}

// 15-bit float for w in (0,1]: 5-bit exp, 10-bit mantissa.
__device__ __forceinline__ unsigned int f15enc(float w) {
    unsigned int u = __float_as_uint(w);           // w >= 0
    u += 0x0FFFu + ((u >> 13) & 1u);               // RNE to 10-bit mantissa
    int e5 = (int)(u >> 23) - 96;
    if (e5 <= 0) return 0u;                        // underflow -> 0 (negligible)
    unsigned int m = (u >> 13) & 0x3FFu;
    if (e5 > 31) { e5 = 31; m = 0x3FFu; }
    return ((unsigned int)e5 << 10) | m;
}
__device__ __forceinline__ float f15dec(unsigned int f) {
    if (f == 0u) return 0.0f;
    return __uint_as_float((((f >> 10) + 96u) << 23) | ((f & 0x3FFu) << 13));
}

// exclusive prefix of x across the 64-lane wave
__device__ __forceinline__ int wave_excl_scan_int(int x, int lane) {
    int inc = x;
    #pragma unroll
    for (int off = 1; off < 64; off <<= 1) {
        int y = __shfl_up(inc, off);
        if (lane >= off) inc += y;
    }
    return inc - x;
}

// wave0: exclusive scan of src[0..nb) (nb <= 1024) into dst (LDS).
__device__ __forceinline__ void scan_btot(const int* __restrict__ src,
                                          int* dst, int nb, int tid) {
    if (tid < 64) {
        int v[16];
        #pragma unroll
        for (int j = 0; j < 16; ++j) {
            int idx = tid * 16 + j;
            v[j] = (idx < nb) ? src[idx] : 0;
        }
        int loc = 0;
        #pragma unroll
        for (int j = 0; j < 16; ++j) loc += v[j];
        int ex = wave_excl_scan_int(loc, tid);
        int run = ex;
        #pragma unroll
        for (int j = 0; j < 16; ++j) {
            int idx = tid * 16 + j;
            if (idx < nb) { dst[idx] = run; run += v[j]; }
        }
    }
}

// prep: x16 = bf16(x); zero out/bounds; per-chunk LDS histogram.
__global__ void __launch_bounds__(256)
k_prep(ushort4* __restrict__ x164, const float4* __restrict__ x4,
       float* __restrict__ out, int* __restrict__ gstart, int* __restrict__ gend,
       const int* __restrict__ col, int* __restrict__ ghist,
       int n, int e, int nb, int nblk) {
    __shared__ int h[NBMAX];
    int tid = threadIdx.x, blk = blockIdx.x;
    int i = blk * 256 + tid;
    int tot = n * (NIN / 4);
    if (i < tot) {
        float4 v = x4[i];
        ushort4 hh;
        hh.x = f2bf(v.x); hh.y = f2bf(v.y); hh.z = f2bf(v.z); hh.w = f2bf(v.w);
        x164[i] = hh;
    }
    if (i < GSEG * NIN) out[i] = 0.0f;
    if (i < GSEG) { gstart[i] = 0; gend[i] = 0; }
    if (blk < nblk) {
        for (int j = tid; j < NBMAX; j += 256) h[j] = 0;
        __syncthreads();
        int base = blk * CHUNK;
        int end = base + CHUNK; if (end > e) end = e;
        for (int j = base + tid; j < end; j += 256) atomicAdd(&h[col[j] >> BSH], 1);
        __syncthreads();
        for (int b = tid; b < nb; b += 256) ghist[blk * nb + b] = h[b];
    }
}

// scanA: per-bucket exclusive scan across chunks (wave0); segment bounds.
// NO global atomics (deg handled by k_deg2 from sorted bins).
__global__ void __launch_bounds__(256)
k_scanA(int* __restrict__ ghist, int* __restrict__ btot,
        const int* __restrict__ seg, int* __restrict__ gstart,
        int* __restrict__ gend, int nblk, int nb, int n) {
    int tid = threadIdx.x;
    int b = blockIdx.x;   // grid = nb
    if (tid < 64) {
        int lane = tid;
        int v[8];
        #pragma unroll
        for (int j = 0; j < 8; ++j) {
            int idx = lane * 8 + j;
            v[j] = (idx < nblk) ? ghist[idx * nb + b] : 0;
        }
        int loc = 0;
        #pragma unroll
        for (int j = 0; j < 8; ++j) loc += v[j];
        int ex = wave_excl_scan_int(loc, lane);
        int run = ex;
        #pragma unroll
        for (int j = 0; j < 8; ++j) {
            int idx = lane * 8 + j;
            if (idx < nblk) { int t = v[j]; ghist[idx * nb + b] = run; run += t; }
        }
        if (lane == 63) btot[b] = ex + loc;
    }
    int gsz = gridDim.x * 256;
    for (int i = b * 256 + tid; i < n; i += gsz) {
        int s = seg[i];
        if (i == 0 || seg[i - 1] != s) gstart[s] = i;
        if (i == n - 1 || seg[i + 1] != s) gend[s] = i + 1;
    }
}

// scatter: records (r, cl|f15(ew)) sorted by bucket in LDS, contiguous copy-out.
__global__ void __launch_bounds__(256)
k_scatter(const int* __restrict__ row, const int* __restrict__ col,
          const float* __restrict__ ew, const int* __restrict__ ghist,
          const int* __restrict__ btot, uint2* __restrict__ bins,
          int e, int nb) {
    __shared__ int h[NBMAX];
    __shared__ int loff[NBMAX];
    __shared__ int gdst[NBMAX];
    __shared__ int bb[NBMAX];
    __shared__ uint2 recs[CHUNK];
    __shared__ unsigned short rb[CHUNK];
    int tid = threadIdx.x, blk = blockIdx.x;
    int base = blk * CHUNK;
    int end = base + CHUNK; if (end > e) end = e;
    int cntc = end - base;

    for (int i = tid; i < NBMAX; i += 256) h[i] = 0;
    __syncthreads();
    for (int i = base + tid; i < end; i += 256) atomicAdd(&h[col[i] >> BSH], 1);
    __syncthreads();
    if (tid < 64) {
        int v[16];
        #pragma unroll
        for (int j = 0; j < 16; ++j) {
            int idx = tid * 16 + j;
            v[j] = (idx < nb) ? h[idx] : 0;
        }
        int loc = 0;
        #pragma unroll
        for (int j = 0; j < 16; ++j) loc += v[j];
        int ex = wave_excl_scan_int(loc, tid);
        int run = ex;
        #pragma unroll
        for (int j = 0; j < 16; ++j) {
            int idx = tid * 16 + j;
            if (idx < nb) { loff[idx] = run; run += v[j]; }
        }
    }
    scan_btot(btot, bb, nb, tid);
    __syncthreads();
    for (int b = tid; b < nb; b += 256) gdst[b] = bb[b] + ghist[blk * nb + b];
    for (int i = tid; i < NBMAX; i += 256) h[i] = 0;
    __syncthreads();
    for (int i = base + tid; i < end; i += 256) {
        int c = col[i], r = row[i];
        int b = c >> BSH;
        uint2 rec;
        rec.x = (unsigned int)r;
        rec.y = ((unsigned int)(c & (BND - 1)) << 15) | f15enc(ew[i]);
        int k = atomicAdd(&h[b], 1);
        int idx = loff[b] + k;
        recs[idx] = rec;
        rb[idx] = (unsigned short)b;
    }
    __syncthreads();
    for (int i = tid; i < cntc; i += 256) {
        int b = rb[i];
        bins[(size_t)gdst[b] + (i - loff[b])] = recs[i];
    }
}

// deg2: one block per bucket, accumulate degree in LDS from the bucket's
// CONTIGUOUS record range, write dinv coalesced. Zero global atomics.
__global__ void __launch_bounds__(256)
k_deg2(const uint2* __restrict__ bins, const int* __restrict__ btot,
       float* __restrict__ dinv, int n, int nb) {
    __shared__ float sdeg[BND];
    __shared__ int bb[NBMAX];
    int tid = threadIdx.x;
    int b = blockIdx.x;
    int c0 = b << BSH;
    if (tid < BND) sdeg[tid] = 0.0f;
    scan_btot(btot, bb, nb, tid);
    __syncthreads();
    int s0 = bb[b], tot = btot[b];
    for (int i = tid; i < tot; i += 256) {
        uint2 rec = bins[(size_t)s0 + i];
        int cl = (int)((rec.y >> 15) & (BND - 1));
        atomicAdd(&sdeg[cl], f15dec(rec.y & 0x7FFFu));
    }
    __syncthreads();
    if (tid < BND && c0 + tid < n) dinv[c0 + tid] = rsqrtf(sdeg[tid] + 1.0f);
}

// Fused build+gather: build rows(u32)+weights(f32) tiles in LDS with FULL
// baked weight (dinv[r] random L2-hot read, own dinv from LDS), then gather:
// 8 nodes/wave, 8 lanes/node, uint4 (8 bf16) x-rows. No global ELL, no
// decodes or dinv lookups in the inner loop.
__global__ void __launch_bounds__(256)
k_bg(const uint2* __restrict__ bins, const int* __restrict__ btot,
     const float* __restrict__ dinv, const ushort* __restrict__ x16,
     ushort* __restrict__ agg16, const float* __restrict__ Wp,
     const float* __restrict__ bp, float* __restrict__ score, int n, int nb) {
    __shared__ unsigned int rows[BND * TS];
    __shared__ float wts[BND * TS];
    __shared__ float sdv[BND];
    __shared__ int scnt[BND];
    __shared__ int bb[NBMAX];
    __shared__ int ovr_cl[OVRMAX];
    __shared__ int ovr_r[OVRMAX];
    __shared__ float ovr_w[OVRMAX];
    __shared__ int ovn;
    int tid = threadIdx.x;
    int b = blockIdx.x;
    int c0 = b << BSH;

    if (tid < BND) {
        scnt[tid] = 0;
        int c = c0 + tid;
        sdv[tid] = dinv[c < n ? c : (n - 1)];
    }
    if (tid == 0) ovn = 0;
    scan_btot(btot, bb, nb, tid);
    __syncthreads();

    int s0 = bb[b], tot = btot[b];
    for (int i = tid; i < tot; i += 256) {
        uint2 rec = bins[(size_t)s0 + i];
        int cl = (int)((rec.y >> 15) & (BND - 1));
        int r = (int)rec.x;
        float w = f15dec(rec.y & 0x7FFFu) * dinv[r] * sdv[cl];
        int slot = atomicAdd(&scnt[cl], 1);
        if (slot < CAP) {
            rows[cl * TS + slot] = (unsigned int)r;
            wts[cl * TS + slot] = w;
        } else {
            int oi = atomicAdd(&ovn, 1);
            if (oi < OVRMAX) { ovr_cl[oi] = cl; ovr_r[oi] = r; ovr_w[oi] = w; }
        }
    }
    __syncthreads();

    int lane = tid & 63, wv = tid >> 6;
    int o = lane >> 3, l = lane & 7;
    const float4* wp4 = (const float4*)Wp;
    float4 w0 = wp4[2 * l], w1 = wp4[2 * l + 1];
    float bp0 = bp[0];
    const uint4* xr4 = (const uint4*)x16;
    int nov = ovn;

    #pragma unroll
    for (int it = 0; it < BND / 32; ++it) {
        int bl = it * 32 + wv * 8;          // first local node of this wave
        int nl = bl + o;
        int c = c0 + nl;
        bool valid = c < n;
        int cc = valid ? c : (n - 1);
        int cr = scnt[nl];
        int m = valid ? (cr < CAP ? cr : CAP) : 0;
        float di = sdv[nl];

        int pr0 = (int)rows[nl * TS + 2 * l];
        float pw0 = wts[nl * TS + 2 * l];
        int pr1 = (int)rows[nl * TS + 2 * l + 1];
        float pw1 = wts[nl * TS + 2 * l + 1];

        uint4 xs = xr4[(size_t)cc * 8 + l];
        float s2 = di * di;
        float a0 = s2 * bflo(xs.x), a1 = s2 * bfhi(xs.x);
        float a2 = s2 * bflo(xs.y), a3 = s2 * bfhi(xs.y);
        float a4 = s2 * bflo(xs.z), a5 = s2 * bfhi(xs.z);
        float a6 = s2 * bflo(xs.w), a7 = s2 * bfhi(xs.w);

        int base = lane & 56;
        #pragma unroll
        for (int k = 0; k < 8; ++k) {
            int rk = __shfl((k & 1) ? pr1 : pr0, base + (k >> 1));
            float wk = __shfl((k & 1) ? pw1 : pw0, base + (k >> 1));
            bool v = k < m;
            int r = v ? rk : 0;
            float w = v ? wk : 0.0f;
            uint4 xr = xr4[(size_t)r * 8 + l];
            a0 = fmaf(w, bflo(xr.x), a0); a1 = fmaf(w, bfhi(xr.x), a1);
            a2 = fmaf(w, bflo(xr.y), a2); a3 = fmaf(w, bfhi(xr.y), a3);
            a4 = fmaf(w, bflo(xr.z), a4); a5 = fmaf(w, bfhi(xr.z), a5);
            a6 = fmaf(w, bflo(xr.w), a6); a7 = fmaf(w, bfhi(xr.w), a7);
        }
        if (__any(m > 8)) {
            #pragma unroll
            for (int k = 8; k < CAP; ++k) {
                int rk = __shfl((k & 1) ? pr1 : pr0, base + (k >> 1));
                float wk = __shfl((k & 1) ? pw1 : pw0, base + (k >> 1));
                bool v = k < m;
                int r = v ? rk : 0;
                float w = v ? wk : 0.0f;
                uint4 xr = xr4[(size_t)r * 8 + l];
                a0 = fmaf(w, bflo(xr.x), a0); a1 = fmaf(w, bfhi(xr.x), a1);
                a2 = fmaf(w, bflo(xr.y), a2); a3 = fmaf(w, bfhi(xr.y), a3);
                a4 = fmaf(w, bflo(xr.z), a4); a5 = fmaf(w, bfhi(xr.z), a5);
                a6 = fmaf(w, bflo(xr.w), a6); a7 = fmaf(w, bfhi(xr.w), a7);
            }
        }
        // overflow side-list (rare: deg > CAP)
        for (int i = 0; i < nov; ++i) {
            int cl = ovr_cl[i];
            if (cl >= bl && cl < bl + 8) {
                int r = ovr_r[i];
                float wm = (cl == nl) ? ovr_w[i] : 0.0f;
                uint4 xr = xr4[(size_t)r * 8 + l];
                a0 = fmaf(wm, bflo(xr.x), a0); a1 = fmaf(wm, bfhi(xr.x), a1);
                a2 = fmaf(wm, bflo(xr.y), a2); a3 = fmaf(wm, bfhi(xr.y), a3);
                a4 = fmaf(wm, bflo(xr.z), a4); a5 = fmaf(wm, bfhi(xr.z), a5);
                a6 = fmaf(wm, bflo(xr.w), a6); a7 = fmaf(wm, bfhi(xr.w), a7);
            }
        }

        if (valid) {
            uint4 ho;
            ho.x = pack2bf(a0, a1); ho.y = pack2bf(a2, a3);
            ho.z = pack2bf(a4, a5); ho.w = pack2bf(a6, a7);
            ((uint4*)agg16)[(size_t)cc * 8 + l] = ho;
        }
        float part = a0 * w0.x + a1 * w0.y + a2 * w0.z + a3 * w0.w
                   + a4 * w1.x + a5 * w1.y + a6 * w1.z + a7 * w1.w;
        part += __shfl_xor(part, 1);
        part += __shfl_xor(part, 2);
        part += __shfl_xor(part, 4);
        if (l == 0 && valid) score[c] = part + bp0;
    }
}

// POOL_SPLIT blocks per graph. Fused per-graph softmax; W column in 16 NAMED
// float4s; node agg row staged via LDS broadcast; 4 FMA chains; prefetch.
#define WLOAD(i) float4 wq##i = make_float4(We[(4*(i)+0)*NIN+lane], We[(4*(i)+1)*NIN+lane], \
                                            We[(4*(i)+2)*NIN+lane], We[(4*(i)+3)*NIN+lane]);
#define WSTEP(i) { float4 av = *(const float4*)&als[wv][4*(i)]; \
    e0 = fmaf(av.x, wq##i.x, e0); e1 = fmaf(av.y, wq##i.y, e1); \
    e2 = fmaf(av.z, wq##i.z, e2); e3 = fmaf(av.w, wq##i.w, e3); }

__global__ void __launch_bounds__(256)
k_pool(const ushort* __restrict__ agg16, const float* __restrict__ score,
       const float* __restrict__ We, const float* __restrict__ be,
       const int* __restrict__ gstart, const int* __restrict__ gend,
       float* __restrict__ out) {
    int g = blockIdx.x / POOL_SPLIT;
    int p = blockIdx.x % POOL_SPLIT;
    int tid = threadIdx.x;
    int wv = tid >> 6, lane = tid & 63;
    int s = gstart[g], e = gend[g];

    __shared__ float red[4];
    __shared__ float bc;

    float mx = -3.402823466e38f;
    for (int i = s + tid; i < e; i += 256) mx = fmaxf(mx, score[i]);
    #pragma unroll
    for (int off = 32; off > 0; off >>= 1) mx = fmaxf(mx, __shfl_xor(mx, off));
    if (lane == 0) red[wv] = mx;
    __syncthreads();
    if (tid == 0) bc = fmaxf(fmaxf(red[0], red[1]), fmaxf(red[2], red[3]));
    __syncthreads();
    float m = bc;
    __syncthreads();

    float sm = 0.0f;
    for (int i = s + tid; i < e; i += 256) sm += __expf(score[i] - m);
    sm = wave_reduce_sum(sm);
    if (lane == 0) red[wv] = sm;
    __syncthreads();
    if (tid == 0) bc = red[0] + red[1] + red[2] + red[3];
    __syncthreads();
    float invz = (bc > 0.0f) ? 1.0f / bc : 0.0f;

    WLOAD(0) WLOAD(1) WLOAD(2) WLOAD(3) WLOAD(4) WLOAD(5) WLOAD(6) WLOAD(7)
    WLOAD(8) WLOAD(9) WLOAD(10) WLOAD(11) WLOAD(12) WLOAD(13) WLOAD(14) WLOAD(15)
    float bj = be[lane];

    __shared__ float als[4][NIN];
    __shared__ float part[4][NIN];

    const int stride = POOL_SPLIT * 4;
    int n = s + p * 4 + wv;
    float acc = 0.0f;

    float a_cur = 0.0f, sw_cur = 0.0f;
    if (n < e) {
        a_cur = bf2f(agg16[(size_t)n * NIN + lane]);
        sw_cur = __expf(score[n] - m) * invz;
    }
    while (n < e) {
        int nn = n + stride;
        bool vn = nn < e;
        int ni = vn ? nn : n;
        float a_nxt = bf2f(agg16[(size_t)ni * NIN + lane]);   // prefetch
        float sw_nxt = __expf(score[ni] - m) * invz;

        als[wv][lane] = a_cur;
        float e0 = bj, e1 = 0.0f, e2 = 0.0f, e3 = 0.0f;
        WSTEP(0) WSTEP(1) WSTEP(2) WSTEP(3) WSTEP(4) WSTEP(5) WSTEP(6) WSTEP(7)
        WSTEP(8) WSTEP(9) WSTEP(10) WSTEP(11) WSTEP(12) WSTEP(13) WSTEP(14) WSTEP(15)
        float emb = fmaxf(e0 + e1 + e2 + e3, 0.0f);
        acc = fmaf(sw_cur, emb, acc);

        a_cur = a_nxt; sw_cur = sw_nxt;
        n = nn;
    }
    part[wv][lane] = acc;
    __syncthreads();
    if (wv == 0) {
        float r = part[0][lane] + part[1][lane] + part[2][lane] + part[3][lane];
        atomicAdd(&out[(size_t)g * NIN + lane], r);
    }
}

extern "C" void kernel_launch(void* const* d_in, const int* in_sizes, int n_in,
                              void* d_out, int out_size, void* d_ws, size_t ws_size,
                              hipStream_t stream) {
    const float* x  = (const float*)d_in[0];
    const float* We = (const float*)d_in[1];
    const float* be = (const float*)d_in[2];
    const float* Wp = (const float*)d_in[3];
    const float* bp = (const float*)d_in[4];
    const float* ew = (const float*)d_in[5];
    const int* eidx = (const int*)d_in[6];
    const int* seg  = (const int*)d_in[7];

    int N = in_sizes[0] / NIN;
    int E = in_sizes[5];
    const int* row = eidx;
    const int* col = eidx + E;
    int nb   = (N + BND - 1) / BND;       // 782
    int nblk = (E + CHUNK - 1) / CHUNK;   // 391

    char* w = (char*)d_ws;
    auto alloc = [&](size_t bytes) {
        char* p = w;
        w += (bytes + 255) & ~(size_t)255;
        return p;
    };
    unsigned short* x16    = (unsigned short*)alloc((size_t)N * NIN * sizeof(short));
    unsigned short* agg16  = (unsigned short*)alloc((size_t)N * NIN * sizeof(short));
    float*          dinv   = (float*)alloc((size_t)N * sizeof(float));
    uint2*          bins   = (uint2*)alloc((size_t)E * sizeof(uint2));
    int*            ghist  = (int*)  alloc((size_t)nblk * nb * sizeof(int));
    int*            btot   = (int*)  alloc((size_t)nb * sizeof(int));
    float*          score  = (float*)alloc((size_t)N * sizeof(float));
    int*            gstart = (int*)  alloc(GSEG * sizeof(int));
    int*            gend   = (int*)  alloc(GSEG * sizeof(int));
    float* out = (float*)d_out;

    int b = 256;
    int g_prep = (N * (NIN / 4) + b - 1) / b;   // 6250 >= nblk

    k_prep<<<g_prep, b, 0, stream>>>((ushort4*)x16, (const float4*)x, out, gstart,
                                     gend, col, ghist, N, E, nb, nblk);
    k_scanA<<<nb, b, 0, stream>>>(ghist, btot, seg, gstart, gend, nblk, nb, N);
    k_scatter<<<nblk, b, 0, stream>>>(row, col, ew, ghist, btot, bins, E, nb);
    k_deg2<<<nb, b, 0, stream>>>(bins, btot, dinv, N, nb);
    k_bg<<<nb, b, 0, stream>>>(bins, btot, dinv, x16, agg16, Wp, bp, score, N, nb);
    k_pool<<<GSEG * POOL_SPLIT, b, 0, stream>>>(agg16, score, We, be, gstart, gend, out);
}